// Round 1
// baseline (1531.318 us; speedup 1.0000x reference)
//
#include <hip/hip_runtime.h>
#include <stdint.h>

#define NODES 60000
#define NPAD  60032   // 469 * 128
#define EDGES 240000
#define KDIM  768
#define HF    768     // HEADS * F_OUT
#define NCAT  1536    // [proj | skip]
#define FOUT  128

typedef unsigned short u16;
typedef __bf16 bf16x8 __attribute__((ext_vector_type(8)));
typedef float f32x4 __attribute__((ext_vector_type(4)));

__device__ __forceinline__ float bf2f(u16 u) {
  union { uint32_t i; float f; } v; v.i = ((uint32_t)u) << 16; return v.f;
}
__device__ __forceinline__ u16 f2bf(float f) {
  union { float f; uint32_t i; } v; v.f = f;
  return (u16)((v.i + 0x7FFF + ((v.i >> 16) & 1)) >> 16);
}

// ---------------- convert x (f32 -> bf16, zero pad rows) ----------------
__global__ __launch_bounds__(256) void convert_x_k(const float* __restrict__ x, u16* __restrict__ xb) {
  const size_t g = ((size_t)blockIdx.x * 256 + threadIdx.x) * 4;
  if (g >= (size_t)NPAD * KDIM) return;
  ushort4 o;
  if (g < (size_t)NODES * KDIM) {
    const float4 v = *(const float4*)(x + g);
    o.x = f2bf(v.x); o.y = f2bf(v.y); o.z = f2bf(v.z); o.w = f2bf(v.w);
  } else { o.x = o.y = o.z = o.w = 0; }
  *(ushort4*)(xb + g) = o;
}

// ---------------- weight prep: WcatT[n][k] = [W | skip][k][n], bf16 ----------------
__global__ __launch_bounds__(256) void prep_wcat_k(const float* __restrict__ W, const float* __restrict__ SK,
                                                   u16* __restrict__ WT) {
  const int t = blockIdx.x * 256 + threadIdx.x;
  if (t >= NCAT * KDIM) return;
  const int n = t % NCAT, k = t / NCAT;
  const float v = (n < HF) ? W[(size_t)k * HF + n] : SK[(size_t)k * HF + (n - HF)];
  WT[(size_t)n * KDIM + k] = f2bf(v);
}

// ---------------- waa[k][h] = sum_f W[k][h*128+f] * a[h][f]  (h<6: src, h>=6: tgt) ----------------
__global__ __launch_bounds__(256) void prep_waa_k(const float* __restrict__ W, const float* __restrict__ a_s,
                                                  const float* __restrict__ a_t, float* __restrict__ waa) {
  const int t = blockIdx.x * 256 + threadIdx.x;
  if (t >= KDIM * 12) return;
  const int h2 = t % 12, k = t / 12;
  const float* a = (h2 < 6) ? a_s : a_t;
  const int h = (h2 < 6) ? h2 : h2 - 6;
  const float* wrow = W + (size_t)k * HF + h * FOUT;
  const float* arow = a + h * FOUT;
  float s = 0.f;
  for (int f = 0; f < FOUT; ++f) s += wrow[f] * arow[f];
  waa[t] = s;
}

// ---------------- s_src/s_tgt = x @ waa : one wave per node ----------------
__global__ __launch_bounds__(256) void s_kernel(const u16* __restrict__ xb, const float* __restrict__ waa,
                                                float* __restrict__ ss, float* __restrict__ stg) {
  __shared__ float wl[KDIM * 13];
  for (int i = threadIdx.x; i < KDIM * 12; i += 256) { int k = i / 12, h = i % 12; wl[k * 13 + h] = waa[i]; }
  __syncthreads();
  const int node = blockIdx.x * 4 + (threadIdx.x >> 6);
  const int lane = threadIdx.x & 63;
  if (node >= NODES) return;
  float p[12];
#pragma unroll
  for (int h = 0; h < 12; ++h) p[h] = 0.f;
#pragma unroll
  for (int i = 0; i < 12; ++i) {
    const int k = i * 64 + lane;
    const float xv = bf2f(xb[(size_t)node * KDIM + k]);
#pragma unroll
    for (int h = 0; h < 12; ++h) p[h] += xv * wl[k * 13 + h];
  }
#pragma unroll
  for (int h = 0; h < 12; ++h) {
    float v = p[h];
    for (int off = 32; off > 0; off >>= 1) v += __shfl_down(v, off, 64);
    if (lane == 0) { if (h < 6) ss[node * 6 + h] = v; else stg[node * 6 + (h - 6)] = v; }
  }
}

// ---------------- CSR build ----------------
__global__ __launch_bounds__(256) void hist_k(const int* __restrict__ tgt, int* __restrict__ deg) {
  const int e = blockIdx.x * 256 + threadIdx.x;
  if (e < EDGES) atomicAdd(&deg[tgt[e]], 1);
}

__global__ __launch_bounds__(1024) void scan_k(int* __restrict__ degcur, int* __restrict__ rp) {
  __shared__ int buf[1024];
  __shared__ int carry;
  const int tid = threadIdx.x;
  if (tid == 0) carry = 0;
  __syncthreads();
  for (int base = 0; base < NODES; base += 1024) {
    const int i = base + tid;
    const int v = (i < NODES) ? degcur[i] : 0;
    buf[tid] = v; __syncthreads();
    for (int off = 1; off < 1024; off <<= 1) {
      const int t2 = (tid >= off) ? buf[tid - off] : 0;
      __syncthreads();
      buf[tid] += t2;
      __syncthreads();
    }
    const int excl = buf[tid] - v + carry;
    if (i < NODES) { rp[i] = excl; degcur[i] = excl; }
    __syncthreads();
    if (tid == 1023) carry += buf[1023];
    __syncthreads();
  }
  if (tid == 0) rp[NODES] = carry;
}

__global__ __launch_bounds__(256) void scatter_k(const int* __restrict__ srcv, const int* __restrict__ tgt,
                                                 int* __restrict__ cur, int* __restrict__ esrc) {
  const int e = blockIdx.x * 256 + threadIdx.x;
  if (e < EDGES) {
    const int t = tgt[e];
    const int pos = atomicAdd(&cur[t], 1);
    esrc[pos] = srcv[e];
  }
}

// ---------------- per-target softmax -> alpha per sorted edge ----------------
__global__ __launch_bounds__(256) void attn_k(const int* __restrict__ rp, const int* __restrict__ esrc,
                                              const float* __restrict__ ss, const float* __restrict__ stg,
                                              float* __restrict__ alp) {
  const int t = blockIdx.x * 256 + threadIdx.x;
  if (t >= NODES) return;
  const int b = rp[t], e = rp[t + 1];
  if (b == e) return;
  float sth[6], m[6], d[6];
#pragma unroll
  for (int h = 0; h < 6; ++h) { sth[h] = stg[t * 6 + h]; m[h] = -1e30f; d[h] = 0.f; }
  for (int j = b; j < e; ++j) {
    const int s = esrc[j];
#pragma unroll
    for (int h = 0; h < 6; ++h) {
      float sc = ss[s * 6 + h] + sth[h];
      sc = sc > 0.f ? sc : 0.2f * sc;
      m[h] = fmaxf(m[h], sc);
    }
  }
  for (int j = b; j < e; ++j) {
    const int s = esrc[j];
#pragma unroll
    for (int h = 0; h < 6; ++h) {
      float sc = ss[s * 6 + h] + sth[h];
      sc = sc > 0.f ? sc : 0.2f * sc;
      const float ev = expf(sc - m[h]);
      d[h] += ev;
      alp[(size_t)j * 6 + h] = ev;
    }
  }
  float iv[6];
#pragma unroll
  for (int h = 0; h < 6; ++h) iv[h] = 1.f / (d[h] + 1e-16f);
  for (int j = b; j < e; ++j) {
#pragma unroll
    for (int h = 0; h < 6; ++h) alp[(size_t)j * 6 + h] *= iv[h];
  }
}

// ---------------- bf16 MFMA GEMM: C[NPAD x 1536] = A[NPAD x 768] * B, B given as BT[1536 x 768] ----------------
__global__ __launch_bounds__(256) void gemm_k(const u16* __restrict__ A, const u16* __restrict__ BT,
                                              u16* __restrict__ C) {
  __shared__ u16 As[2][128 * 32];
  __shared__ u16 Bs[2][128 * 32];
  const int tid = threadIdx.x;
  const int lane = tid & 63;
  const int w = tid >> 6;
  const int wm = w >> 1, wn = w & 1;
  const int r16 = lane & 15, g4 = lane >> 4;
  const size_t rowBase = (size_t)blockIdx.y * 128;
  const int colBase = blockIdx.x * 128;

  // staging: 512 16B-chunks per tile; chunk c -> row c>>2, k-offset (c&3)*8
  const int c0 = tid, c1 = tid + 256;
  const size_t aoff0 = (rowBase + (c0 >> 2)) * KDIM + (c0 & 3) * 8;
  const size_t aoff1 = (rowBase + (c1 >> 2)) * KDIM + (c1 & 3) * 8;
  const size_t boff0 = ((size_t)(colBase + (c0 >> 2))) * KDIM + (c0 & 3) * 8;
  const size_t boff1 = ((size_t)(colBase + (c1 >> 2))) * KDIM + (c1 & 3) * 8;

  auto stage = [&](int buf, int k0) {
    __builtin_amdgcn_global_load_lds((__attribute__((address_space(1))) void*)(A + aoff0 + k0),
                                     (__attribute__((address_space(3))) void*)(&As[buf][w * 512]), 16, 0, 0);
    __builtin_amdgcn_global_load_lds((__attribute__((address_space(1))) void*)(A + aoff1 + k0),
                                     (__attribute__((address_space(3))) void*)(&As[buf][2048 + w * 512]), 16, 0, 0);
    __builtin_amdgcn_global_load_lds((__attribute__((address_space(1))) void*)(BT + boff0 + k0),
                                     (__attribute__((address_space(3))) void*)(&Bs[buf][w * 512]), 16, 0, 0);
    __builtin_amdgcn_global_load_lds((__attribute__((address_space(1))) void*)(BT + boff1 + k0),
                                     (__attribute__((address_space(3))) void*)(&Bs[buf][2048 + w * 512]), 16, 0, 0);
  };

  f32x4 acc[4][4];
#pragma unroll
  for (int i = 0; i < 4; ++i)
#pragma unroll
    for (int j = 0; j < 4; ++j) acc[i][j] = f32x4{0.f, 0.f, 0.f, 0.f};

  stage(0, 0);
  __syncthreads();
  for (int ks = 0; ks < 24; ++ks) {
    const int buf = ks & 1;
    if (ks < 23) stage(buf ^ 1, (ks + 1) * 32);
    bf16x8 af[4], bv[4];
#pragma unroll
    for (int i = 0; i < 4; ++i)
      af[i] = *(const bf16x8*)(&As[buf][(wm * 64 + i * 16 + r16) * 32 + g4 * 8]);
#pragma unroll
    for (int j = 0; j < 4; ++j)
      bv[j] = *(const bf16x8*)(&Bs[buf][(wn * 64 + j * 16 + r16) * 32 + g4 * 8]);
#pragma unroll
    for (int i = 0; i < 4; ++i)
#pragma unroll
      for (int j = 0; j < 4; ++j)
        acc[i][j] = __builtin_amdgcn_mfma_f32_16x16x32_bf16(af[i], bv[j], acc[i][j], 0, 0, 0);
    __syncthreads();
  }

#pragma unroll
  for (int i = 0; i < 4; ++i) {
    const size_t row0 = rowBase + wm * 64 + i * 16 + g4 * 4;
#pragma unroll
    for (int j = 0; j < 4; ++j) {
      const int col = colBase + wn * 64 + j * 16 + r16;
#pragma unroll
      for (int r = 0; r < 4; ++r)
        C[(row0 + r) * NCAT + col] = f2bf(acc[i][j][r]);
    }
  }
}

// ---------------- aggregation: one wave per target node ----------------
template <int MODE>
__global__ __launch_bounds__(256) void aggregate_k(const u16* __restrict__ Cb, const int* __restrict__ rp,
                                                   const int* __restrict__ esrc, const float* __restrict__ alp,
                                                   const float* __restrict__ bias, u16* __restrict__ xnext,
                                                   float* __restrict__ outf) {
  const int t = blockIdx.x * 4 + (threadIdx.x >> 6);
  const int lane = threadIdx.x & 63;
  if (t >= NODES) return;
  float acc[12];
  {
    const u16* sk = Cb + (size_t)t * NCAT + HF;
#pragma unroll
    for (int k = 0; k < 12; ++k) acc[k] = bf2f(sk[lane + 64 * k]);
  }
  const int b = rp[t], e = rp[t + 1];
  for (int j = b; j < e; ++j) {
    const int s = esrc[j];
    const float* al = alp + (size_t)j * 6;
    float a6[6];
#pragma unroll
    for (int h = 0; h < 6; ++h) a6[h] = al[h];
    const u16* pr = Cb + (size_t)s * NCAT;
#pragma unroll
    for (int k = 0; k < 12; ++k)
      acc[k] += a6[k >> 1] * bf2f(pr[lane + 64 * k]);  // head(col) = (lane+64k)>>7 = k>>1 for lane<64
  }
  if (MODE == 0) {
#pragma unroll
    for (int k = 0; k < 12; ++k) {
      const int col = lane + 64 * k;
      float v = acc[k] + bias[col];
      v = v > 0.f ? v : expm1f(v);
      xnext[(size_t)t * HF + col] = f2bf(v);
    }
  } else {
    const float e0 = acc[0] + acc[2] + acc[4] + acc[6] + acc[8] + acc[10];
    const float e1 = acc[1] + acc[3] + acc[5] + acc[7] + acc[9] + acc[11];
    outf[(size_t)t * FOUT + lane] = e0 * (1.0f / 6.0f) + bias[lane];
    outf[(size_t)t * FOUT + 64 + lane] = e1 * (1.0f / 6.0f) + bias[64 + lane];
  }
}

// ---------------- workspace layout ----------------
#define OFF_XBF 0ull
#define OFF_CB  92209152ull
#define OFF_WT  276627456ull
#define OFF_WAA 278986752ull
#define OFF_SS  279023616ull
#define OFF_ST  280463616ull
#define OFF_ALP 281903616ull
#define OFF_RP  287663616ull
#define OFF_CUR 287903744ull
#define OFF_ESR 288143872ull

extern "C" void kernel_launch(void* const* d_in, const int* in_sizes, int n_in,
                              void* d_out, int out_size, void* d_ws, size_t ws_size,
                              hipStream_t stream) {
  const float* x = (const float*)d_in[0];
  // edge_index in dict order is d_in[1]; fall back to arg order (last) if sizes say otherwise
  const int ei = (in_sizes[1] == 2 * EDGES) ? 1 : 16;
  const int base = (ei == 1) ? 2 : 1;
  const float *W[3], *AS[3], *AT[3], *SK[3], *B[3];
  for (int l = 0; l < 3; ++l) {
    W[l]  = (const float*)d_in[base + 5 * l + 0];
    AS[l] = (const float*)d_in[base + 5 * l + 1];
    AT[l] = (const float*)d_in[base + 5 * l + 2];
    SK[l] = (const float*)d_in[base + 5 * l + 3];
    B[l]  = (const float*)d_in[base + 5 * l + 4];
  }
  const int* edges = (const int*)d_in[ei];
  const int* srcv = edges;
  const int* tgtv = edges + EDGES;
  float* out = (float*)d_out;

  char* ws = (char*)d_ws;
  u16* xbf = (u16*)(ws + OFF_XBF);
  u16* Cb  = (u16*)(ws + OFF_CB);
  u16* WT  = (u16*)(ws + OFF_WT);
  float* waa = (float*)(ws + OFF_WAA);
  float* ss  = (float*)(ws + OFF_SS);
  float* stg = (float*)(ws + OFF_ST);
  float* alp = (float*)(ws + OFF_ALP);
  int* rp  = (int*)(ws + OFF_RP);
  int* cur = (int*)(ws + OFF_CUR);
  int* esr = (int*)(ws + OFF_ESR);

  // CSR build (once per call)
  hipMemsetAsync(cur, 0, NODES * sizeof(int), stream);
  hist_k<<<(EDGES + 255) / 256, 256, 0, stream>>>(tgtv, cur);
  scan_k<<<1, 1024, 0, stream>>>(cur, rp);
  scatter_k<<<(EDGES + 255) / 256, 256, 0, stream>>>(srcv, tgtv, cur, esr);

  convert_x_k<<<45024, 256, 0, stream>>>(x, xbf);

  for (int l = 0; l < 3; ++l) {
    prep_wcat_k<<<(NCAT * KDIM + 255) / 256, 256, 0, stream>>>(W[l], SK[l], WT);
    prep_waa_k<<<(KDIM * 12 + 255) / 256, 256, 0, stream>>>(W[l], AS[l], AT[l], waa);
    s_kernel<<<15000, 256, 0, stream>>>(xbf, waa, ss, stg);
    gemm_k<<<dim3(12, 469), 256, 0, stream>>>(xbf, WT, Cb);
    attn_k<<<(NODES + 255) / 256, 256, 0, stream>>>(rp, esr, ss, stg, alp);
    if (l < 2)
      aggregate_k<0><<<15000, 256, 0, stream>>>(Cb, rp, esr, alp, B[l], xbf, nullptr);
    else
      aggregate_k<1><<<15000, 256, 0, stream>>>(Cb, rp, esr, alp, B[l], nullptr, out);
  }
}

// Round 2
// 1156.305 us; speedup vs baseline: 1.3243x; 1.3243x over previous
//
#include <hip/hip_runtime.h>
#include <stdint.h>

#define NODES 60000
#define NPAD  60032   // 469 * 128
#define EDGES 240000
#define KDIM  768
#define HF    768     // HEADS * F_OUT
#define NCAT  1536    // [proj | skip]
#define FOUT  128

typedef unsigned short u16;
typedef __bf16 bf16x8 __attribute__((ext_vector_type(8)));
typedef float f32x4 __attribute__((ext_vector_type(4)));

__device__ __forceinline__ float bf2f(u16 u) {
  union { uint32_t i; float f; } v; v.i = ((uint32_t)u) << 16; return v.f;
}
__device__ __forceinline__ u16 f2bf(float f) {
  union { float f; uint32_t i; } v; v.f = f;
  return (u16)((v.i + 0x7FFF + ((v.i >> 16) & 1)) >> 16);
}

// ---------------- convert x (f32 -> bf16, zero pad rows) ----------------
__global__ __launch_bounds__(256) void convert_x_k(const float* __restrict__ x, u16* __restrict__ xb) {
  const size_t g = ((size_t)blockIdx.x * 256 + threadIdx.x) * 4;
  if (g >= (size_t)NPAD * KDIM) return;
  ushort4 o;
  if (g < (size_t)NODES * KDIM) {
    const float4 v = *(const float4*)(x + g);
    o.x = f2bf(v.x); o.y = f2bf(v.y); o.z = f2bf(v.z); o.w = f2bf(v.w);
  } else { o.x = o.y = o.z = o.w = 0; }
  *(ushort4*)(xb + g) = o;
}

// ---------------- weight prep (LDS-tiled transpose): WcatT[n][k] = [W | skip][k][n], bf16 ----------------
__global__ __launch_bounds__(256) void prep_wcat_k(const float* __restrict__ W, const float* __restrict__ SK,
                                                   u16* __restrict__ WT) {
  __shared__ u16 tile[32][33];
  const int n0 = blockIdx.x * 32, k0 = blockIdx.y * 32;
  const int tx = threadIdx.x & 31, ty = threadIdx.x >> 5;  // 32 x 8
#pragma unroll
  for (int r = 0; r < 32; r += 8) {
    const int k = k0 + ty + r, n = n0 + tx;
    const float v = (n < HF) ? W[(size_t)k * HF + n] : SK[(size_t)k * HF + (n - HF)];
    tile[ty + r][tx] = f2bf(v);
  }
  __syncthreads();
#pragma unroll
  for (int r = 0; r < 32; r += 8) {
    const int n = n0 + ty + r, k = k0 + tx;
    WT[(size_t)n * KDIM + k] = tile[tx][ty + r];
  }
}

// ---------------- CSR build ----------------
__global__ __launch_bounds__(256) void hist_k(const int* __restrict__ tgt, int* __restrict__ deg) {
  const int e = blockIdx.x * 256 + threadIdx.x;
  if (e < EDGES) atomicAdd(&deg[tgt[e]], 1);
}

__global__ __launch_bounds__(1024) void scan_k(int* __restrict__ degcur, int* __restrict__ rp) {
  __shared__ int buf[1024];
  __shared__ int carry;
  const int tid = threadIdx.x;
  if (tid == 0) carry = 0;
  __syncthreads();
  for (int base = 0; base < NODES; base += 1024) {
    const int i = base + tid;
    const int v = (i < NODES) ? degcur[i] : 0;
    buf[tid] = v; __syncthreads();
    for (int off = 1; off < 1024; off <<= 1) {
      const int t2 = (tid >= off) ? buf[tid - off] : 0;
      __syncthreads();
      buf[tid] += t2;
      __syncthreads();
    }
    const int excl = buf[tid] - v + carry;
    if (i < NODES) { rp[i] = excl; degcur[i] = excl; }
    __syncthreads();
    if (tid == 1023) carry += buf[1023];
    __syncthreads();
  }
  if (tid == 0) rp[NODES] = carry;
}

__global__ __launch_bounds__(256) void scatter_k(const int* __restrict__ srcv, const int* __restrict__ tgt,
                                                 int* __restrict__ cur, int* __restrict__ esrc) {
  const int e = blockIdx.x * 256 + threadIdx.x;
  if (e < EDGES) {
    const int t = tgt[e];
    const int pos = atomicAdd(&cur[t], 1);
    esrc[pos] = srcv[e];
  }
}

// ---------------- per-target softmax -> alpha per sorted edge ----------------
__global__ __launch_bounds__(256) void attn_k(const int* __restrict__ rp, const int* __restrict__ esrc,
                                              const float* __restrict__ ss, const float* __restrict__ stg,
                                              float* __restrict__ alp) {
  const int t = blockIdx.x * 256 + threadIdx.x;
  if (t >= NODES) return;
  const int b = rp[t], e = rp[t + 1];
  if (b == e) return;
  float sth[6], m[6], d[6];
#pragma unroll
  for (int h = 0; h < 6; ++h) { sth[h] = stg[t * 6 + h]; m[h] = -1e30f; d[h] = 0.f; }
  for (int j = b; j < e; ++j) {
    const int s = esrc[j];
#pragma unroll
    for (int h = 0; h < 6; ++h) {
      float sc = ss[s * 6 + h] + sth[h];
      sc = sc > 0.f ? sc : 0.2f * sc;
      m[h] = fmaxf(m[h], sc);
    }
  }
  for (int j = b; j < e; ++j) {
    const int s = esrc[j];
#pragma unroll
    for (int h = 0; h < 6; ++h) {
      float sc = ss[s * 6 + h] + sth[h];
      sc = sc > 0.f ? sc : 0.2f * sc;
      const float ev = expf(sc - m[h]);
      d[h] += ev;
      alp[(size_t)j * 6 + h] = ev;
    }
  }
  float iv[6];
#pragma unroll
  for (int h = 0; h < 6; ++h) iv[h] = 1.f / (d[h] + 1e-16f);
  for (int j = b; j < e; ++j) {
#pragma unroll
    for (int h = 0; h < 6; ++h) alp[(size_t)j * 6 + h] *= iv[h];
  }
}

// ---------------- bf16 MFMA GEMM + fused attention-score epilogue ----------------
// C[NPAD x 1536] = A[NPAD x 768] * B  (B given as BT[1536 x 768])
// blocks with bx<6 also emit ss/stg for head bx from the f32 accumulators.
__global__ __launch_bounds__(256) void gemm_k(const u16* __restrict__ A, const u16* __restrict__ BT,
                                              u16* __restrict__ C,
                                              const float* __restrict__ a_src, const float* __restrict__ a_tgt,
                                              float* __restrict__ ss, float* __restrict__ stg) {
  __shared__ u16 As[2][128 * 32];
  __shared__ u16 Bs[2][128 * 32];
  __shared__ float spS[2][128];
  __shared__ float spT[2][128];
  const int tid = threadIdx.x;
  const int lane = tid & 63;
  const int w = tid >> 6;
  const int wm = w >> 1, wn = w & 1;
  const int r16 = lane & 15, g4 = lane >> 4;

  // XCD-chunked bijective swizzle (m204): each XCD gets a contiguous chunk of
  // work-space; col-blocks (x fastest) sharing an A panel stay on one XCD.
  const int NWG = 12 * 469;             // 5628
  const int q = NWG / 8, rr = NWG % 8;  // 703, 4
  const int orig = blockIdx.x;
  const int xcd = orig & 7, idx = orig >> 3;
  const int wg = (xcd < rr ? xcd * (q + 1) : rr * (q + 1) + (xcd - rr) * q) + idx;
  const int bx = wg % 12, by = wg / 12;

  const size_t rowBase = (size_t)by * 128;
  const int colBase = bx * 128;

  const int c0 = tid, c1 = tid + 256;
  const size_t aoff0 = (rowBase + (c0 >> 2)) * KDIM + (c0 & 3) * 8;
  const size_t aoff1 = (rowBase + (c1 >> 2)) * KDIM + (c1 & 3) * 8;
  const size_t boff0 = ((size_t)(colBase + (c0 >> 2))) * KDIM + (c0 & 3) * 8;
  const size_t boff1 = ((size_t)(colBase + (c1 >> 2))) * KDIM + (c1 & 3) * 8;

  auto stage = [&](int buf, int k0) {
    __builtin_amdgcn_global_load_lds((__attribute__((address_space(1))) void*)(A + aoff0 + k0),
                                     (__attribute__((address_space(3))) void*)(&As[buf][w * 512]), 16, 0, 0);
    __builtin_amdgcn_global_load_lds((__attribute__((address_space(1))) void*)(A + aoff1 + k0),
                                     (__attribute__((address_space(3))) void*)(&As[buf][2048 + w * 512]), 16, 0, 0);
    __builtin_amdgcn_global_load_lds((__attribute__((address_space(1))) void*)(BT + boff0 + k0),
                                     (__attribute__((address_space(3))) void*)(&Bs[buf][w * 512]), 16, 0, 0);
    __builtin_amdgcn_global_load_lds((__attribute__((address_space(1))) void*)(BT + boff1 + k0),
                                     (__attribute__((address_space(3))) void*)(&Bs[buf][2048 + w * 512]), 16, 0, 0);
  };

  f32x4 acc[4][4];
#pragma unroll
  for (int i = 0; i < 4; ++i)
#pragma unroll
    for (int j = 0; j < 4; ++j) acc[i][j] = f32x4{0.f, 0.f, 0.f, 0.f};

  stage(0, 0);
  __syncthreads();
  for (int ks = 0; ks < 24; ++ks) {
    const int buf = ks & 1;
    if (ks < 23) stage(buf ^ 1, (ks + 1) * 32);
    bf16x8 af[4], bv[4];
#pragma unroll
    for (int i = 0; i < 4; ++i)
      af[i] = *(const bf16x8*)(&As[buf][(wm * 64 + i * 16 + r16) * 32 + g4 * 8]);
#pragma unroll
    for (int j = 0; j < 4; ++j)
      bv[j] = *(const bf16x8*)(&Bs[buf][(wn * 64 + j * 16 + r16) * 32 + g4 * 8]);
#pragma unroll
    for (int i = 0; i < 4; ++i)
#pragma unroll
      for (int j = 0; j < 4; ++j)
        acc[i][j] = __builtin_amdgcn_mfma_f32_16x16x32_bf16(af[i], bv[j], acc[i][j], 0, 0, 0);
    __syncthreads();
  }

  // C write
#pragma unroll
  for (int i = 0; i < 4; ++i) {
    const size_t row0 = rowBase + wm * 64 + i * 16 + g4 * 4;
#pragma unroll
    for (int j = 0; j < 4; ++j) {
      const int col = colBase + wn * 64 + j * 16 + r16;
#pragma unroll
      for (int r = 0; r < 4; ++r)
        C[(row0 + r) * NCAT + col] = f2bf(acc[i][j][r]);
    }
  }

  // fused attention-score epilogue: s_{src,tgt}[row, h=bx] = sum_f acc*a[h,f]
  if (bx < 6) {
    float avS[4], avT[4];
#pragma unroll
    for (int j = 0; j < 4; ++j) {
      const int f = wn * 64 + j * 16 + r16;
      avS[j] = a_src[bx * FOUT + f];
      avT[j] = a_tgt[bx * FOUT + f];
    }
#pragma unroll
    for (int i = 0; i < 4; ++i) {
#pragma unroll
      for (int r = 0; r < 4; ++r) {
        float pS = 0.f, pT = 0.f;
#pragma unroll
        for (int j = 0; j < 4; ++j) { pS += acc[i][j][r] * avS[j]; pT += acc[i][j][r] * avT[j]; }
#pragma unroll
        for (int off = 1; off < 16; off <<= 1) { pS += __shfl_xor(pS, off, 64); pT += __shfl_xor(pT, off, 64); }
        if (r16 == 0) {
          spS[wn][wm * 64 + i * 16 + g4 * 4 + r] = pS;
          spT[wn][wm * 64 + i * 16 + g4 * 4 + r] = pT;
        }
      }
    }
    __syncthreads();
    if (tid < 128) {
      const size_t row = rowBase + tid;
      if (row < NODES) {
        ss[row * 6 + bx] = spS[0][tid] + spS[1][tid];
        stg[row * 6 + bx] = spT[0][tid] + spT[1][tid];
      }
    }
  }
}

// ---------------- aggregation: one wave per target node, vectorized ----------------
// lane covers cols {lane*4 + 256k + c : k<3, c<4}; head(col) = (lane>>5) + 2k
template <int MODE>
__global__ __launch_bounds__(256) void aggregate_k(const u16* __restrict__ Cb, const int* __restrict__ rp,
                                                   const int* __restrict__ esrc, const float* __restrict__ alp,
                                                   const float* __restrict__ bias, u16* __restrict__ xnext,
                                                   float* __restrict__ outf) {
  const int t = blockIdx.x * 4 + (threadIdx.x >> 6);
  const int lane = threadIdx.x & 63;
  if (t >= NODES) return;
  const int l4 = lane * 4;
  float acc[3][4];
  {
    const u16* sk = Cb + (size_t)t * NCAT + HF;
#pragma unroll
    for (int k = 0; k < 3; ++k) {
      const ushort4 v = *(const ushort4*)(sk + l4 + 256 * k);
      acc[k][0] = bf2f(v.x); acc[k][1] = bf2f(v.y); acc[k][2] = bf2f(v.z); acc[k][3] = bf2f(v.w);
    }
  }
  const int b = rp[t], e = rp[t + 1];
  const int h0 = lane >> 5;
  for (int j = b; j < e; ++j) {
    const int s = esrc[j];
    const float2 a01 = *(const float2*)(alp + (size_t)j * 6);
    const float2 a23 = *(const float2*)(alp + (size_t)j * 6 + 2);
    const float2 a45 = *(const float2*)(alp + (size_t)j * 6 + 4);
    const float a6[6] = {a01.x, a01.y, a23.x, a23.y, a45.x, a45.y};
    const u16* pr = Cb + (size_t)s * NCAT;
#pragma unroll
    for (int k = 0; k < 3; ++k) {
      const ushort4 v = *(const ushort4*)(pr + l4 + 256 * k);
      const float a = a6[h0 + 2 * k];
      acc[k][0] += a * bf2f(v.x); acc[k][1] += a * bf2f(v.y);
      acc[k][2] += a * bf2f(v.z); acc[k][3] += a * bf2f(v.w);
    }
  }
  if (MODE == 0) {
#pragma unroll
    for (int k = 0; k < 3; ++k) {
      ushort4 o;
      float v0 = acc[k][0] + bias[l4 + 256 * k];
      float v1 = acc[k][1] + bias[l4 + 256 * k + 1];
      float v2 = acc[k][2] + bias[l4 + 256 * k + 2];
      float v3 = acc[k][3] + bias[l4 + 256 * k + 3];
      o.x = f2bf(v0 > 0.f ? v0 : expm1f(v0));
      o.y = f2bf(v1 > 0.f ? v1 : expm1f(v1));
      o.z = f2bf(v2 > 0.f ? v2 : expm1f(v2));
      o.w = f2bf(v3 > 0.f ? v3 : expm1f(v3));
      *(ushort4*)(xnext + (size_t)t * HF + l4 + 256 * k) = o;
    }
  } else {
    float4 o;
    float* op = &o.x;
#pragma unroll
    for (int c = 0; c < 4; ++c) {
      const float s3 = acc[0][c] + acc[1][c] + acc[2][c];
      const float tot = s3 + __shfl_xor(s3, 32, 64);
      op[c] = tot * (1.0f / 6.0f);
    }
    if (lane < 32) {
      const int f = (lane & 31) * 4;
      o.x += bias[f]; o.y += bias[f + 1]; o.z += bias[f + 2]; o.w += bias[f + 3];
      *(float4*)(outf + (size_t)t * FOUT + f) = o;
    }
  }
}

// ---------------- workspace layout ----------------
#define OFF_XBF 0ull
#define OFF_CB  92209152ull
#define OFF_WT  276627456ull
#define OFF_WAA 278986752ull
#define OFF_SS  279023616ull
#define OFF_ST  280463616ull
#define OFF_ALP 281903616ull
#define OFF_RP  287663616ull
#define OFF_CUR 287903744ull
#define OFF_ESR 288143872ull

extern "C" void kernel_launch(void* const* d_in, const int* in_sizes, int n_in,
                              void* d_out, int out_size, void* d_ws, size_t ws_size,
                              hipStream_t stream) {
  const float* x = (const float*)d_in[0];
  const int ei = (in_sizes[1] == 2 * EDGES) ? 1 : 16;
  const int base = (ei == 1) ? 2 : 1;
  const float *W[3], *AS[3], *AT[3], *SK[3], *B[3];
  for (int l = 0; l < 3; ++l) {
    W[l]  = (const float*)d_in[base + 5 * l + 0];
    AS[l] = (const float*)d_in[base + 5 * l + 1];
    AT[l] = (const float*)d_in[base + 5 * l + 2];
    SK[l] = (const float*)d_in[base + 5 * l + 3];
    B[l]  = (const float*)d_in[base + 5 * l + 4];
  }
  const int* edges = (const int*)d_in[ei];
  const int* srcv = edges;
  const int* tgtv = edges + EDGES;
  float* out = (float*)d_out;

  char* ws = (char*)d_ws;
  u16* xbf = (u16*)(ws + OFF_XBF);
  u16* Cb  = (u16*)(ws + OFF_CB);
  u16* WT  = (u16*)(ws + OFF_WT);
  float* ss  = (float*)(ws + OFF_SS);
  float* stg = (float*)(ws + OFF_ST);
  float* alp = (float*)(ws + OFF_ALP);
  int* rp  = (int*)(ws + OFF_RP);
  int* cur = (int*)(ws + OFF_CUR);
  int* esr = (int*)(ws + OFF_ESR);

  // CSR build
  hipMemsetAsync(cur, 0, NODES * sizeof(int), stream);
  hist_k<<<(EDGES + 255) / 256, 256, 0, stream>>>(tgtv, cur);
  scan_k<<<1, 1024, 0, stream>>>(cur, rp);
  scatter_k<<<(EDGES + 255) / 256, 256, 0, stream>>>(srcv, tgtv, cur, esr);

  convert_x_k<<<45024, 256, 0, stream>>>(x, xbf);

  for (int l = 0; l < 3; ++l) {
    prep_wcat_k<<<dim3(48, 24), 256, 0, stream>>>(W[l], SK[l], WT);
    gemm_k<<<12 * 469, 256, 0, stream>>>(xbf, WT, Cb, AS[l], AT[l], ss, stg);
    attn_k<<<(NODES + 255) / 256, 256, 0, stream>>>(rp, esr, ss, stg, alp);
    if (l < 2)
      aggregate_k<0><<<15000, 256, 0, stream>>>(Cb, rp, esr, alp, B[l], xbf, nullptr);
    else
      aggregate_k<1><<<15000, 256, 0, stream>>>(Cb, rp, esr, alp, B[l], nullptr, out);
  }
}

// Round 3
// 1044.633 us; speedup vs baseline: 1.4659x; 1.1069x over previous
//
#include <hip/hip_runtime.h>
#include <stdint.h>

#define NODES 60000
#define NPAD  60032   // 469 * 128
#define EDGES 240000
#define KDIM  768
#define HF    768     // HEADS * F_OUT
#define FOUT  128

typedef unsigned short u16;
typedef __bf16 bf16x8 __attribute__((ext_vector_type(8)));
typedef float f32x4 __attribute__((ext_vector_type(4)));

__device__ __forceinline__ float bf2f(u16 u) {
  union { uint32_t i; float f; } v; v.i = ((uint32_t)u) << 16; return v.f;
}
__device__ __forceinline__ u16 f2bf(float f) {
  union { float f; uint32_t i; } v; v.f = f;
  return (u16)((v.i + 0x7FFF + ((v.i >> 16) & 1)) >> 16);
}

// ---------------- convert x (f32 -> bf16, zero pad rows) ----------------
__global__ __launch_bounds__(256) void convert_x_k(const float* __restrict__ x, u16* __restrict__ xb) {
  const size_t g = ((size_t)blockIdx.x * 256 + threadIdx.x) * 4;
  if (g >= (size_t)NPAD * KDIM) return;
  ushort4 o;
  if (g < (size_t)NODES * KDIM) {
    const float4 v = *(const float4*)(x + g);
    o.x = f2bf(v.x); o.y = f2bf(v.y); o.z = f2bf(v.z); o.w = f2bf(v.w);
  } else { o.x = o.y = o.z = o.w = 0; }
  *(ushort4*)(xb + g) = o;
}

// ---------------- weight prep (LDS-tiled transpose) ----------------
// MODE 0: WT[n][k] = [W | skip][k][n], n<1536
// MODE 1: WT[n][k] = n<768 ? W[k][n] : mean_h skip[k][h*128 + (n-768)], n<896
template <int MODE>
__global__ __launch_bounds__(256) void prep_wcat_k(const float* __restrict__ W, const float* __restrict__ SK,
                                                   u16* __restrict__ WT) {
  __shared__ u16 tile[32][33];
  const int n0 = blockIdx.x * 32, k0 = blockIdx.y * 32;
  const int tx = threadIdx.x & 31, ty = threadIdx.x >> 5;  // 32 x 8
#pragma unroll
  for (int r = 0; r < 32; r += 8) {
    const int k = k0 + ty + r, n = n0 + tx;
    float v;
    if (n < HF) {
      v = W[(size_t)k * HF + n];
    } else if (MODE == 0) {
      v = SK[(size_t)k * HF + (n - HF)];
    } else {
      const int f = n - HF;
      v = 0.f;
#pragma unroll
      for (int h = 0; h < 6; ++h) v += SK[(size_t)k * HF + h * FOUT + f];
      v *= (1.0f / 6.0f);
    }
    tile[ty + r][tx] = f2bf(v);
  }
  __syncthreads();
#pragma unroll
  for (int r = 0; r < 32; r += 8) {
    const int n = n0 + ty + r, k = k0 + tx;
    WT[(size_t)n * KDIM + k] = tile[tx][ty + r];
  }
}

// ---------------- CSR build ----------------
__global__ __launch_bounds__(256) void hist_k(const int* __restrict__ tgt, int* __restrict__ deg) {
  const int e = blockIdx.x * 256 + threadIdx.x;
  if (e < EDGES) atomicAdd(&deg[tgt[e]], 1);
}

__global__ __launch_bounds__(1024) void scan_k(int* __restrict__ degcur, int* __restrict__ rp) {
  __shared__ int buf[1024];
  __shared__ int carry;
  const int tid = threadIdx.x;
  if (tid == 0) carry = 0;
  __syncthreads();
  for (int base = 0; base < NODES; base += 1024) {
    const int i = base + tid;
    const int v = (i < NODES) ? degcur[i] : 0;
    buf[tid] = v; __syncthreads();
    for (int off = 1; off < 1024; off <<= 1) {
      const int t2 = (tid >= off) ? buf[tid - off] : 0;
      __syncthreads();
      buf[tid] += t2;
      __syncthreads();
    }
    const int excl = buf[tid] - v + carry;
    if (i < NODES) { rp[i] = excl; degcur[i] = excl; }
    __syncthreads();
    if (tid == 1023) carry += buf[1023];
    __syncthreads();
  }
  if (tid == 0) rp[NODES] = carry;
}

__global__ __launch_bounds__(256) void scatter_k(const int* __restrict__ srcv, const int* __restrict__ tgt,
                                                 int* __restrict__ cur, int* __restrict__ esrc) {
  const int e = blockIdx.x * 256 + threadIdx.x;
  if (e < EDGES) {
    const int t = tgt[e];
    const int pos = atomicAdd(&cur[t], 1);
    esrc[pos] = srcv[e];
  }
}

// ---------------- per-target softmax: alpha = exp(sc - max); denom deferred ----------------
__global__ __launch_bounds__(256) void attn_k(const int* __restrict__ rp, const int* __restrict__ esrc,
                                              const float* __restrict__ ss, const float* __restrict__ stg,
                                              float* __restrict__ alp, float* __restrict__ invd) {
  const int t = blockIdx.x * 256 + threadIdx.x;
  if (t >= NODES) return;
  const int b = rp[t], e = rp[t + 1];
  float sth[6], m[6], d[6];
#pragma unroll
  for (int h = 0; h < 6; ++h) { sth[h] = stg[t * 6 + h]; m[h] = -1e30f; d[h] = 0.f; }
  for (int j = b; j < e; ++j) {
    const int s = esrc[j];
#pragma unroll
    for (int h = 0; h < 6; ++h) {
      float sc = ss[s * 6 + h] + sth[h];
      sc = sc > 0.f ? sc : 0.2f * sc;
      m[h] = fmaxf(m[h], sc);
    }
  }
  for (int j = b; j < e; ++j) {
    const int s = esrc[j];
#pragma unroll
    for (int h = 0; h < 6; ++h) {
      float sc = ss[s * 6 + h] + sth[h];
      sc = sc > 0.f ? sc : 0.2f * sc;
      const float ev = expf(sc - m[h]);
      d[h] += ev;
      alp[(size_t)j * 6 + h] = ev;
    }
  }
#pragma unroll
  for (int h = 0; h < 6; ++h) invd[t * 6 + h] = 1.f / (d[h] + 1e-16f);
}

// ---------------- bf16 MFMA GEMM + fused attention-score epilogue ----------------
// C[NPAD x ncat] = A[NPAD x 768] * B  (B given as BT[ncat x 768]); ncat = nbx*128
// blocks with bx<6 also emit ss/stg for head bx from the f32 accumulators.
__global__ __launch_bounds__(256) void gemm_k(const u16* __restrict__ A, const u16* __restrict__ BT,
                                              u16* __restrict__ C,
                                              const float* __restrict__ a_src, const float* __restrict__ a_tgt,
                                              float* __restrict__ ss, float* __restrict__ stg,
                                              int nbx, int ncat) {
  __shared__ u16 As[2][4096];
  __shared__ u16 Bs[2][4096];
  // score scratch aliases As[0] (dead after the K loop): 512 floats = 2048 B
  float* sp = (float*)&As[0][0];
  const int tid = threadIdx.x;
  const int lane = tid & 63;
  const int w = tid >> 6;
  const int wm = w >> 1, wn = w & 1;
  const int r16 = lane & 15, g4 = lane >> 4;

  // XCD-chunked bijective swizzle (m204)
  const int NWG = nbx * 469;
  const int q = NWG >> 3, rr = NWG & 7;
  const int orig = blockIdx.x;
  const int xcd = orig & 7, idx = orig >> 3;
  const int wg = (xcd < rr ? xcd * (q + 1) : rr * (q + 1) + (xcd - rr) * q) + idx;
  const int bx = wg % nbx, by = wg / nbx;

  const size_t rowBase = (size_t)by * 128;
  const int colBase = bx * 128;

  const int c0 = tid, c1 = tid + 256;
  const size_t aoff0 = (rowBase + (c0 >> 2)) * KDIM + (c0 & 3) * 8;
  const size_t aoff1 = (rowBase + (c1 >> 2)) * KDIM + (c1 & 3) * 8;
  const size_t boff0 = ((size_t)(colBase + (c0 >> 2))) * KDIM + (c0 & 3) * 8;
  const size_t boff1 = ((size_t)(colBase + (c1 >> 2))) * KDIM + (c1 & 3) * 8;

  auto stage = [&](int buf, int k0) {
    __builtin_amdgcn_global_load_lds((__attribute__((address_space(1))) void*)(A + aoff0 + k0),
                                     (__attribute__((address_space(3))) void*)(&As[buf][w * 512]), 16, 0, 0);
    __builtin_amdgcn_global_load_lds((__attribute__((address_space(1))) void*)(A + aoff1 + k0),
                                     (__attribute__((address_space(3))) void*)(&As[buf][2048 + w * 512]), 16, 0, 0);
    __builtin_amdgcn_global_load_lds((__attribute__((address_space(1))) void*)(BT + boff0 + k0),
                                     (__attribute__((address_space(3))) void*)(&Bs[buf][w * 512]), 16, 0, 0);
    __builtin_amdgcn_global_load_lds((__attribute__((address_space(1))) void*)(BT + boff1 + k0),
                                     (__attribute__((address_space(3))) void*)(&Bs[buf][2048 + w * 512]), 16, 0, 0);
  };

  f32x4 acc[4][4];
#pragma unroll
  for (int i = 0; i < 4; ++i)
#pragma unroll
    for (int j = 0; j < 4; ++j) acc[i][j] = f32x4{0.f, 0.f, 0.f, 0.f};

  stage(0, 0);
  __syncthreads();
  for (int ks = 0; ks < 24; ++ks) {
    const int buf = ks & 1;
    if (ks < 23) stage(buf ^ 1, (ks + 1) * 32);
    bf16x8 af[4], bv[4];
#pragma unroll
    for (int i = 0; i < 4; ++i)
      af[i] = *(const bf16x8*)(&As[buf][(wm * 64 + i * 16 + r16) * 32 + g4 * 8]);
#pragma unroll
    for (int j = 0; j < 4; ++j)
      bv[j] = *(const bf16x8*)(&Bs[buf][(wn * 64 + j * 16 + r16) * 32 + g4 * 8]);
#pragma unroll
    for (int i = 0; i < 4; ++i)
#pragma unroll
      for (int j = 0; j < 4; ++j)
        acc[i][j] = __builtin_amdgcn_mfma_f32_16x16x32_bf16(af[i], bv[j], acc[i][j], 0, 0, 0);
    __syncthreads();
  }

  // C write
#pragma unroll
  for (int i = 0; i < 4; ++i) {
    const size_t row0 = rowBase + wm * 64 + i * 16 + g4 * 4;
#pragma unroll
    for (int j = 0; j < 4; ++j) {
      const int col = colBase + wn * 64 + j * 16 + r16;
#pragma unroll
      for (int r = 0; r < 4; ++r)
        C[(row0 + r) * ncat + col] = f2bf(acc[i][j][r]);
    }
  }

  // fused attention-score epilogue
  if (bx < 6) {
    float avS[4], avT[4];
#pragma unroll
    for (int j = 0; j < 4; ++j) {
      const int f = wn * 64 + j * 16 + r16;
      avS[j] = a_src[bx * FOUT + f];
      avT[j] = a_tgt[bx * FOUT + f];
    }
#pragma unroll
    for (int i = 0; i < 4; ++i) {
#pragma unroll
      for (int r = 0; r < 4; ++r) {
        float pS = 0.f, pT = 0.f;
#pragma unroll
        for (int j = 0; j < 4; ++j) { pS += acc[i][j][r] * avS[j]; pT += acc[i][j][r] * avT[j]; }
#pragma unroll
        for (int off = 1; off < 16; off <<= 1) { pS += __shfl_xor(pS, off, 64); pT += __shfl_xor(pT, off, 64); }
        if (r16 == 0) {
          const int row = wm * 64 + i * 16 + g4 * 4 + r;
          sp[wn * 128 + row] = pS;
          sp[256 + wn * 128 + row] = pT;
        }
      }
    }
    __syncthreads();
    if (tid < 128) {
      const size_t row = rowBase + tid;
      if (row < NODES) {
        ss[row * 6 + bx] = sp[tid] + sp[128 + tid];
        stg[row * 6 + bx] = sp[256 + tid] + sp[384 + tid];
      }
    }
  }
}

// ---------------- aggregation: one wave per target node, vectorized, deferred denom ----------------
// lane covers cols {lane*4 + 256k + c : k<3, c<4}; head(col) = (lane>>5) + 2k
template <int MODE>
__global__ __launch_bounds__(256) void aggregate_k(const u16* __restrict__ Cb, const int* __restrict__ rp,
                                                   const int* __restrict__ esrc, const float* __restrict__ alp,
                                                   const float* __restrict__ invd, const float* __restrict__ bias,
                                                   u16* __restrict__ xnext, float* __restrict__ outf) {
  constexpr int ncat = (MODE == 0) ? 1536 : 896;
  const int t = blockIdx.x * 4 + (threadIdx.x >> 6);
  const int lane = threadIdx.x & 63;
  if (t >= NODES) return;
  const int l4 = lane * 4;
  const int h0 = lane >> 5;
  float macc[3][4];
#pragma unroll
  for (int k = 0; k < 3; ++k)
#pragma unroll
    for (int c = 0; c < 4; ++c) macc[k][c] = 0.f;

  const int b = rp[t], e = rp[t + 1];
  int j = b;
  for (; j + 1 < e; j += 2) {
    const int s0 = esrc[j], s1 = esrc[j + 1];
    const float2 p0 = *(const float2*)(alp + (size_t)j * 6);
    const float2 p1 = *(const float2*)(alp + (size_t)j * 6 + 2);
    const float2 p2 = *(const float2*)(alp + (size_t)j * 6 + 4);
    const float2 q0 = *(const float2*)(alp + (size_t)(j + 1) * 6);
    const float2 q1 = *(const float2*)(alp + (size_t)(j + 1) * 6 + 2);
    const float2 q2 = *(const float2*)(alp + (size_t)(j + 1) * 6 + 4);
    const float a0[6] = {p0.x, p0.y, p1.x, p1.y, p2.x, p2.y};
    const float a1[6] = {q0.x, q0.y, q1.x, q1.y, q2.x, q2.y};
    const u16* pr0 = Cb + (size_t)s0 * ncat;
    const u16* pr1 = Cb + (size_t)s1 * ncat;
#pragma unroll
    for (int k = 0; k < 3; ++k) {
      const ushort4 v0 = *(const ushort4*)(pr0 + l4 + 256 * k);
      const ushort4 v1 = *(const ushort4*)(pr1 + l4 + 256 * k);
      const float aa0 = a0[h0 + 2 * k], aa1 = a1[h0 + 2 * k];
      macc[k][0] += aa0 * bf2f(v0.x) + aa1 * bf2f(v1.x);
      macc[k][1] += aa0 * bf2f(v0.y) + aa1 * bf2f(v1.y);
      macc[k][2] += aa0 * bf2f(v0.z) + aa1 * bf2f(v1.z);
      macc[k][3] += aa0 * bf2f(v0.w) + aa1 * bf2f(v1.w);
    }
  }
  if (j < e) {
    const int s0 = esrc[j];
    const float2 p0 = *(const float2*)(alp + (size_t)j * 6);
    const float2 p1 = *(const float2*)(alp + (size_t)j * 6 + 2);
    const float2 p2 = *(const float2*)(alp + (size_t)j * 6 + 4);
    const float a0[6] = {p0.x, p0.y, p1.x, p1.y, p2.x, p2.y};
    const u16* pr0 = Cb + (size_t)s0 * ncat;
#pragma unroll
    for (int k = 0; k < 3; ++k) {
      const ushort4 v0 = *(const ushort4*)(pr0 + l4 + 256 * k);
      const float aa0 = a0[h0 + 2 * k];
      macc[k][0] += aa0 * bf2f(v0.x);
      macc[k][1] += aa0 * bf2f(v0.y);
      macc[k][2] += aa0 * bf2f(v0.z);
      macc[k][3] += aa0 * bf2f(v0.w);
    }
  }

  float inv[3];
#pragma unroll
  for (int k = 0; k < 3; ++k) inv[k] = invd[t * 6 + h0 + 2 * k];

  if (MODE == 0) {
    const u16* sk = Cb + (size_t)t * ncat + HF;
#pragma unroll
    for (int k = 0; k < 3; ++k) {
      const ushort4 s4 = *(const ushort4*)(sk + l4 + 256 * k);
      ushort4 o;
      float v0 = macc[k][0] * inv[k] + bf2f(s4.x) + bias[l4 + 256 * k];
      float v1 = macc[k][1] * inv[k] + bf2f(s4.y) + bias[l4 + 256 * k + 1];
      float v2 = macc[k][2] * inv[k] + bf2f(s4.z) + bias[l4 + 256 * k + 2];
      float v3 = macc[k][3] * inv[k] + bf2f(s4.w) + bias[l4 + 256 * k + 3];
      o.x = f2bf(v0 > 0.f ? v0 : expm1f(v0));
      o.y = f2bf(v1 > 0.f ? v1 : expm1f(v1));
      o.z = f2bf(v2 > 0.f ? v2 : expm1f(v2));
      o.w = f2bf(v3 > 0.f ? v3 : expm1f(v3));
      *(ushort4*)(xnext + (size_t)t * HF + l4 + 256 * k) = o;
    }
  } else {
    float4 o;
    float* op = &o.x;
#pragma unroll
    for (int c = 0; c < 4; ++c) {
      const float s3 = macc[0][c] * inv[0] + macc[1][c] * inv[1] + macc[2][c] * inv[2];
      const float tot = s3 + __shfl_xor(s3, 32, 64);
      op[c] = tot * (1.0f / 6.0f);
    }
    if (lane < 32) {
      const int f = lane * 4;
      const ushort4 s4 = *(const ushort4*)(Cb + (size_t)t * ncat + HF + f);
      o.x += bf2f(s4.x) + bias[f];
      o.y += bf2f(s4.y) + bias[f + 1];
      o.z += bf2f(s4.z) + bias[f + 2];
      o.w += bf2f(s4.w) + bias[f + 3];
      *(float4*)(outf + (size_t)t * FOUT + f) = o;
    }
  }
}

// ---------------- workspace layout ----------------
#define OFF_XBF 0ull
#define OFF_CB  92209152ull
#define OFF_WT  276627456ull   // 1536*768*2 = 2359296 B; invd aliases this region between gemm and next prep
#define OFF_SS  279023616ull
#define OFF_ST  280463616ull
#define OFF_ALP 281903616ull
#define OFF_RP  287663616ull
#define OFF_CUR 287903744ull
#define OFF_ESR 288143872ull

extern "C" void kernel_launch(void* const* d_in, const int* in_sizes, int n_in,
                              void* d_out, int out_size, void* d_ws, size_t ws_size,
                              hipStream_t stream) {
  const float* x = (const float*)d_in[0];
  const int ei = (in_sizes[1] == 2 * EDGES) ? 1 : 16;
  const int base = (ei == 1) ? 2 : 1;
  const float *W[3], *AS[3], *AT[3], *SK[3], *B[3];
  for (int l = 0; l < 3; ++l) {
    W[l]  = (const float*)d_in[base + 5 * l + 0];
    AS[l] = (const float*)d_in[base + 5 * l + 1];
    AT[l] = (const float*)d_in[base + 5 * l + 2];
    SK[l] = (const float*)d_in[base + 5 * l + 3];
    B[l]  = (const float*)d_in[base + 5 * l + 4];
  }
  const int* edges = (const int*)d_in[ei];
  const int* srcv = edges;
  const int* tgtv = edges + EDGES;
  float* out = (float*)d_out;

  char* ws = (char*)d_ws;
  u16* xbf = (u16*)(ws + OFF_XBF);
  u16* Cb  = (u16*)(ws + OFF_CB);
  u16* WT  = (u16*)(ws + OFF_WT);
  float* invd = (float*)(ws + OFF_WT);   // aliases WT: live only between attn_k and aggregate_k
  float* ss  = (float*)(ws + OFF_SS);
  float* stg = (float*)(ws + OFF_ST);
  float* alp = (float*)(ws + OFF_ALP);
  int* rp  = (int*)(ws + OFF_RP);
  int* cur = (int*)(ws + OFF_CUR);
  int* esr = (int*)(ws + OFF_ESR);

  // CSR build
  hipMemsetAsync(cur, 0, NODES * sizeof(int), stream);
  hist_k<<<(EDGES + 255) / 256, 256, 0, stream>>>(tgtv, cur);
  scan_k<<<1, 1024, 0, stream>>>(cur, rp);
  scatter_k<<<(EDGES + 255) / 256, 256, 0, stream>>>(srcv, tgtv, cur, esr);

  convert_x_k<<<45024, 256, 0, stream>>>(x, xbf);

  for (int l = 0; l < 3; ++l) {
    const int nbx = (l < 2) ? 12 : 7;
    const int ncat = nbx * 128;
    if (l < 2)
      prep_wcat_k<0><<<dim3(48, 24), 256, 0, stream>>>(W[l], SK[l], WT);
    else
      prep_wcat_k<1><<<dim3(28, 24), 256, 0, stream>>>(W[l], SK[l], WT);
    gemm_k<<<nbx * 469, 256, 0, stream>>>(xbf, WT, Cb, AS[l], AT[l], ss, stg, nbx, ncat);
    attn_k<<<(NODES + 255) / 256, 256, 0, stream>>>(rp, esr, ss, stg, alp, invd);
    if (l < 2)
      aggregate_k<0><<<15000, 256, 0, stream>>>(Cb, rp, esr, alp, invd, B[l], xbf, nullptr);
    else
      aggregate_k<1><<<15000, 256, 0, stream>>>(Cb, rp, esr, alp, invd, B[l], nullptr, out);
  }
}

// Round 4
// 987.073 us; speedup vs baseline: 1.5514x; 1.0583x over previous
//
#include <hip/hip_runtime.h>
#include <stdint.h>

#define NODES 60000
#define NPAD  60032   // 469 * 128
#define EDGES 240000
#define KDIM  768
#define HF    768     // HEADS * F_OUT
#define FOUT  128

typedef unsigned short u16;
typedef __bf16 bf16x8 __attribute__((ext_vector_type(8)));
typedef float f32x4 __attribute__((ext_vector_type(4)));

__device__ __forceinline__ float bf2f(u16 u) {
  union { uint32_t i; float f; } v; v.i = ((uint32_t)u) << 16; return v.f;
}
__device__ __forceinline__ u16 f2bf(float f) {
  union { float f; uint32_t i; } v; v.f = f;
  return (u16)((v.i + 0x7FFF + ((v.i >> 16) & 1)) >> 16);
}

// ---------------- convert x (f32 -> bf16, zero pad rows) ----------------
__global__ __launch_bounds__(256) void convert_x_k(const float* __restrict__ x, u16* __restrict__ xb) {
  const size_t g = ((size_t)blockIdx.x * 256 + threadIdx.x) * 4;
  if (g >= (size_t)NPAD * KDIM) return;
  ushort4 o;
  if (g < (size_t)NODES * KDIM) {
    const float4 v = *(const float4*)(x + g);
    o.x = f2bf(v.x); o.y = f2bf(v.y); o.z = f2bf(v.z); o.w = f2bf(v.w);
  } else { o.x = o.y = o.z = o.w = 0; }
  *(ushort4*)(xb + g) = o;
}

// ---------------- weight prep (LDS-tiled transpose) ----------------
// MODE 0: WT[n][k] = [W | skip][k][n], n<1536
// MODE 1: WT[n][k] = n<768 ? W[k][n] : mean_h skip[k][h*128 + (n-768)], n<896
template <int MODE>
__global__ __launch_bounds__(256) void prep_wcat_k(const float* __restrict__ W, const float* __restrict__ SK,
                                                   u16* __restrict__ WT) {
  __shared__ u16 tile[32][33];
  const int n0 = blockIdx.x * 32, k0 = blockIdx.y * 32;
  const int tx = threadIdx.x & 31, ty = threadIdx.x >> 5;  // 32 x 8
#pragma unroll
  for (int r = 0; r < 32; r += 8) {
    const int k = k0 + ty + r, n = n0 + tx;
    float v;
    if (n < HF) {
      v = W[(size_t)k * HF + n];
    } else if (MODE == 0) {
      v = SK[(size_t)k * HF + (n - HF)];
    } else {
      const int f = n - HF;
      v = 0.f;
#pragma unroll
      for (int h = 0; h < 6; ++h) v += SK[(size_t)k * HF + h * FOUT + f];
      v *= (1.0f / 6.0f);
    }
    tile[ty + r][tx] = f2bf(v);
  }
  __syncthreads();
#pragma unroll
  for (int r = 0; r < 32; r += 8) {
    const int n = n0 + ty + r, k = k0 + tx;
    WT[(size_t)n * KDIM + k] = tile[tx][ty + r];
  }
}

// ---------------- CSR build ----------------
__global__ __launch_bounds__(256) void hist_k(const int* __restrict__ tgt, int* __restrict__ deg) {
  const int e = blockIdx.x * 256 + threadIdx.x;
  if (e < EDGES) atomicAdd(&deg[tgt[e]], 1);
}

__global__ __launch_bounds__(1024) void scan_k(int* __restrict__ degcur, int* __restrict__ rp) {
  __shared__ int buf[1024];
  __shared__ int carry;
  const int tid = threadIdx.x;
  if (tid == 0) carry = 0;
  __syncthreads();
  for (int base = 0; base < NODES; base += 1024) {
    const int i = base + tid;
    const int v = (i < NODES) ? degcur[i] : 0;
    buf[tid] = v; __syncthreads();
    for (int off = 1; off < 1024; off <<= 1) {
      const int t2 = (tid >= off) ? buf[tid - off] : 0;
      __syncthreads();
      buf[tid] += t2;
      __syncthreads();
    }
    const int excl = buf[tid] - v + carry;
    if (i < NODES) { rp[i] = excl; degcur[i] = excl; }
    __syncthreads();
    if (tid == 1023) carry += buf[1023];
    __syncthreads();
  }
  if (tid == 0) rp[NODES] = carry;
}

__global__ __launch_bounds__(256) void scatter_k(const int* __restrict__ srcv, const int* __restrict__ tgt,
                                                 int* __restrict__ cur, int* __restrict__ esrc) {
  const int e = blockIdx.x * 256 + threadIdx.x;
  if (e < EDGES) {
    const int t = tgt[e];
    const int pos = atomicAdd(&cur[t], 1);
    esrc[pos] = srcv[e];
  }
}

// ---------------- per-target softmax: alpha = exp(sc - max); denom deferred ----------------
__global__ __launch_bounds__(256) void attn_k(const int* __restrict__ rp, const int* __restrict__ esrc,
                                              const float* __restrict__ ss, const float* __restrict__ stg,
                                              float* __restrict__ alp, float* __restrict__ invd) {
  const int t = blockIdx.x * 256 + threadIdx.x;
  if (t >= NODES) return;
  const int b = rp[t], e = rp[t + 1];
  float sth[6], m[6], d[6];
#pragma unroll
  for (int h = 0; h < 6; ++h) { sth[h] = stg[t * 6 + h]; m[h] = -1e30f; d[h] = 0.f; }
  for (int j = b; j < e; ++j) {
    const int s = esrc[j];
#pragma unroll
    for (int h = 0; h < 6; ++h) {
      float sc = ss[s * 6 + h] + sth[h];
      sc = sc > 0.f ? sc : 0.2f * sc;
      m[h] = fmaxf(m[h], sc);
    }
  }
  for (int j = b; j < e; ++j) {
    const int s = esrc[j];
#pragma unroll
    for (int h = 0; h < 6; ++h) {
      float sc = ss[s * 6 + h] + sth[h];
      sc = sc > 0.f ? sc : 0.2f * sc;
      const float ev = expf(sc - m[h]);
      d[h] += ev;
      alp[(size_t)j * 6 + h] = ev;
    }
  }
#pragma unroll
  for (int h = 0; h < 6; ++h) invd[t * 6 + h] = 1.f / (d[h] + 1e-16f);
}

// ---------------- bf16 MFMA GEMM + fused attention-score epilogue ----------------
// C[NPAD x ncat] = A[NPAD x 768] * B  (B given as BT[ncat x 768]); ncat = nbx*128
// blocks with bx<6 also emit ss/stg for head bx from the f32 accumulators.
// __launch_bounds__(256,4): cap arch VGPR at 64 so VGPR(64)+AGPR(64)=128 -> 4 waves/SIMD.
__global__ __launch_bounds__(256, 4) void gemm_k(const u16* __restrict__ A, const u16* __restrict__ BT,
                                                 u16* __restrict__ C,
                                                 const float* __restrict__ a_src, const float* __restrict__ a_tgt,
                                                 float* __restrict__ ss, float* __restrict__ stg,
                                                 int nbx, int ncat) {
  __shared__ u16 As[2][4096];
  __shared__ u16 Bs[2][4096];
  // score scratch aliases As[0] (dead after the K loop): 512 floats = 2048 B
  float* sp = (float*)&As[0][0];
  const int tid = threadIdx.x;
  const int lane = tid & 63;
  const int w = tid >> 6;
  const int wm = w >> 1, wn = w & 1;
  const int r16 = lane & 15, g4 = lane >> 4;

  // XCD-chunked bijective swizzle (m204)
  const int NWG = nbx * 469;
  const int q = NWG >> 3, rr = NWG & 7;
  const int orig = blockIdx.x;
  const int xcd = orig & 7, idx = orig >> 3;
  const int wg = (xcd < rr ? xcd * (q + 1) : rr * (q + 1) + (xcd - rr) * q) + idx;
  const int bx = wg % nbx, by = wg / nbx;

  const size_t rowBase = (size_t)by * 128;
  const int colBase = bx * 128;

  const int c0 = tid, c1 = tid + 256;
  const size_t aoff0 = (rowBase + (c0 >> 2)) * KDIM + (c0 & 3) * 8;
  const size_t aoff1 = (rowBase + (c1 >> 2)) * KDIM + (c1 & 3) * 8;
  const size_t boff0 = ((size_t)(colBase + (c0 >> 2))) * KDIM + (c0 & 3) * 8;
  const size_t boff1 = ((size_t)(colBase + (c1 >> 2))) * KDIM + (c1 & 3) * 8;

  auto stage = [&](int buf, int k0) {
    __builtin_amdgcn_global_load_lds((__attribute__((address_space(1))) void*)(A + aoff0 + k0),
                                     (__attribute__((address_space(3))) void*)(&As[buf][w * 512]), 16, 0, 0);
    __builtin_amdgcn_global_load_lds((__attribute__((address_space(1))) void*)(A + aoff1 + k0),
                                     (__attribute__((address_space(3))) void*)(&As[buf][2048 + w * 512]), 16, 0, 0);
    __builtin_amdgcn_global_load_lds((__attribute__((address_space(1))) void*)(BT + boff0 + k0),
                                     (__attribute__((address_space(3))) void*)(&Bs[buf][w * 512]), 16, 0, 0);
    __builtin_amdgcn_global_load_lds((__attribute__((address_space(1))) void*)(BT + boff1 + k0),
                                     (__attribute__((address_space(3))) void*)(&Bs[buf][2048 + w * 512]), 16, 0, 0);
  };

  f32x4 acc[4][4];
#pragma unroll
  for (int i = 0; i < 4; ++i)
#pragma unroll
    for (int j = 0; j < 4; ++j) acc[i][j] = f32x4{0.f, 0.f, 0.f, 0.f};

  stage(0, 0);
  __syncthreads();
  for (int ks = 0; ks < 24; ++ks) {
    const int buf = ks & 1;
    if (ks < 23) stage(buf ^ 1, (ks + 1) * 32);
    bf16x8 af[4], bv[4];
#pragma unroll
    for (int i = 0; i < 4; ++i)
      af[i] = *(const bf16x8*)(&As[buf][(wm * 64 + i * 16 + r16) * 32 + g4 * 8]);
#pragma unroll
    for (int j = 0; j < 4; ++j)
      bv[j] = *(const bf16x8*)(&Bs[buf][(wn * 64 + j * 16 + r16) * 32 + g4 * 8]);
#pragma unroll
    for (int i = 0; i < 4; ++i)
#pragma unroll
      for (int j = 0; j < 4; ++j)
        acc[i][j] = __builtin_amdgcn_mfma_f32_16x16x32_bf16(af[i], bv[j], acc[i][j], 0, 0, 0);
    __syncthreads();
  }

  // C write
#pragma unroll
  for (int i = 0; i < 4; ++i) {
    const size_t row0 = rowBase + wm * 64 + i * 16 + g4 * 4;
#pragma unroll
    for (int j = 0; j < 4; ++j) {
      const int col = colBase + wn * 64 + j * 16 + r16;
#pragma unroll
      for (int r = 0; r < 4; ++r)
        C[(row0 + r) * ncat + col] = f2bf(acc[i][j][r]);
    }
  }

  // fused attention-score epilogue (two passes: S then T, to keep VGPR peak low)
  if (bx < 6) {
#pragma unroll
    for (int pass = 0; pass < 2; ++pass) {
      const float* av = (pass == 0) ? a_src : a_tgt;
      float a4[4];
#pragma unroll
      for (int j = 0; j < 4; ++j) a4[j] = av[bx * FOUT + wn * 64 + j * 16 + r16];
#pragma unroll
      for (int i = 0; i < 4; ++i) {
#pragma unroll
        for (int r = 0; r < 4; ++r) {
          float p = 0.f;
#pragma unroll
          for (int j = 0; j < 4; ++j) p += acc[i][j][r] * a4[j];
#pragma unroll
          for (int off = 1; off < 16; off <<= 1) p += __shfl_xor(p, off, 64);
          if (r16 == 0) {
            const int row = wm * 64 + i * 16 + g4 * 4 + r;
            sp[pass * 256 + wn * 128 + row] = p;
          }
        }
      }
    }
    __syncthreads();
    if (tid < 128) {
      const size_t row = rowBase + tid;
      if (row < NODES) {
        ss[row * 6 + bx] = sp[tid] + sp[128 + tid];
        stg[row * 6 + bx] = sp[256 + tid] + sp[384 + tid];
      }
    }
  }
}

// ---------------- aggregation: one wave per target node, vectorized, deferred denom ----------------
// lane covers cols {lane*4 + 256k + c : k<3, c<4}; head(col) = (lane>>5) + 2k
template <int MODE>
__global__ __launch_bounds__(256) void aggregate_k(const u16* __restrict__ Cb, const int* __restrict__ rp,
                                                   const int* __restrict__ esrc, const float* __restrict__ alp,
                                                   const float* __restrict__ invd, const float* __restrict__ bias,
                                                   u16* __restrict__ xnext, float* __restrict__ outf) {
  constexpr int ncat = (MODE == 0) ? 1536 : 896;
  const int t = blockIdx.x * 4 + (threadIdx.x >> 6);
  const int lane = threadIdx.x & 63;
  if (t >= NODES) return;
  const int l4 = lane * 4;
  const int h0 = lane >> 5;
  float macc[3][4];
#pragma unroll
  for (int k = 0; k < 3; ++k)
#pragma unroll
    for (int c = 0; c < 4; ++c) macc[k][c] = 0.f;

  const int b = rp[t], e = rp[t + 1];
  int j = b;
  for (; j + 1 < e; j += 2) {
    const int s0 = esrc[j], s1 = esrc[j + 1];
    const float2 p0 = *(const float2*)(alp + (size_t)j * 6);
    const float2 p1 = *(const float2*)(alp + (size_t)j * 6 + 2);
    const float2 p2 = *(const float2*)(alp + (size_t)j * 6 + 4);
    const float2 q0 = *(const float2*)(alp + (size_t)(j + 1) * 6);
    const float2 q1 = *(const float2*)(alp + (size_t)(j + 1) * 6 + 2);
    const float2 q2 = *(const float2*)(alp + (size_t)(j + 1) * 6 + 4);
    const float a0[6] = {p0.x, p0.y, p1.x, p1.y, p2.x, p2.y};
    const float a1[6] = {q0.x, q0.y, q1.x, q1.y, q2.x, q2.y};
    const u16* pr0 = Cb + (size_t)s0 * ncat;
    const u16* pr1 = Cb + (size_t)s1 * ncat;
#pragma unroll
    for (int k = 0; k < 3; ++k) {
      const ushort4 v0 = *(const ushort4*)(pr0 + l4 + 256 * k);
      const ushort4 v1 = *(const ushort4*)(pr1 + l4 + 256 * k);
      const float aa0 = a0[h0 + 2 * k], aa1 = a1[h0 + 2 * k];
      macc[k][0] += aa0 * bf2f(v0.x) + aa1 * bf2f(v1.x);
      macc[k][1] += aa0 * bf2f(v0.y) + aa1 * bf2f(v1.y);
      macc[k][2] += aa0 * bf2f(v0.z) + aa1 * bf2f(v1.z);
      macc[k][3] += aa0 * bf2f(v0.w) + aa1 * bf2f(v1.w);
    }
  }
  if (j < e) {
    const int s0 = esrc[j];
    const float2 p0 = *(const float2*)(alp + (size_t)j * 6);
    const float2 p1 = *(const float2*)(alp + (size_t)j * 6 + 2);
    const float2 p2 = *(const float2*)(alp + (size_t)j * 6 + 4);
    const float a0[6] = {p0.x, p0.y, p1.x, p1.y, p2.x, p2.y};
    const u16* pr0 = Cb + (size_t)s0 * ncat;
#pragma unroll
    for (int k = 0; k < 3; ++k) {
      const ushort4 v0 = *(const ushort4*)(pr0 + l4 + 256 * k);
      const float aa0 = a0[h0 + 2 * k];
      macc[k][0] += aa0 * bf2f(v0.x);
      macc[k][1] += aa0 * bf2f(v0.y);
      macc[k][2] += aa0 * bf2f(v0.z);
      macc[k][3] += aa0 * bf2f(v0.w);
    }
  }

  float inv[3];
#pragma unroll
  for (int k = 0; k < 3; ++k) inv[k] = invd[t * 6 + h0 + 2 * k];

  if (MODE == 0) {
    const u16* sk = Cb + (size_t)t * ncat + HF;
#pragma unroll
    for (int k = 0; k < 3; ++k) {
      const ushort4 s4 = *(const ushort4*)(sk + l4 + 256 * k);
      ushort4 o;
      float v0 = macc[k][0] * inv[k] + bf2f(s4.x) + bias[l4 + 256 * k];
      float v1 = macc[k][1] * inv[k] + bf2f(s4.y) + bias[l4 + 256 * k + 1];
      float v2 = macc[k][2] * inv[k] + bf2f(s4.z) + bias[l4 + 256 * k + 2];
      float v3 = macc[k][3] * inv[k] + bf2f(s4.w) + bias[l4 + 256 * k + 3];
      o.x = f2bf(v0 > 0.f ? v0 : expm1f(v0));
      o.y = f2bf(v1 > 0.f ? v1 : expm1f(v1));
      o.z = f2bf(v2 > 0.f ? v2 : expm1f(v2));
      o.w = f2bf(v3 > 0.f ? v3 : expm1f(v3));
      *(ushort4*)(xnext + (size_t)t * HF + l4 + 256 * k) = o;
    }
  } else {
    float4 o;
    float* op = &o.x;
#pragma unroll
    for (int c = 0; c < 4; ++c) {
      const float s3 = macc[0][c] * inv[0] + macc[1][c] * inv[1] + macc[2][c] * inv[2];
      const float tot = s3 + __shfl_xor(s3, 32, 64);
      op[c] = tot * (1.0f / 6.0f);
    }
    if (lane < 32) {
      const int f = lane * 4;
      const ushort4 s4 = *(const ushort4*)(Cb + (size_t)t * ncat + HF + f);
      o.x += bf2f(s4.x) + bias[f];
      o.y += bf2f(s4.y) + bias[f + 1];
      o.z += bf2f(s4.z) + bias[f + 2];
      o.w += bf2f(s4.w) + bias[f + 3];
      *(float4*)(outf + (size_t)t * FOUT + f) = o;
    }
  }
}

// ---------------- workspace layout ----------------
#define OFF_XBF 0ull
#define OFF_CB  92209152ull
#define OFF_WT  276627456ull   // 1536*768*2 = 2359296 B; invd aliases this region between gemm and next prep
#define OFF_SS  279023616ull
#define OFF_ST  280463616ull
#define OFF_ALP 281903616ull
#define OFF_RP  287663616ull
#define OFF_CUR 287903744ull
#define OFF_ESR 288143872ull

extern "C" void kernel_launch(void* const* d_in, const int* in_sizes, int n_in,
                              void* d_out, int out_size, void* d_ws, size_t ws_size,
                              hipStream_t stream) {
  const float* x = (const float*)d_in[0];
  const int ei = (in_sizes[1] == 2 * EDGES) ? 1 : 16;
  const int base = (ei == 1) ? 2 : 1;
  const float *W[3], *AS[3], *AT[3], *SK[3], *B[3];
  for (int l = 0; l < 3; ++l) {
    W[l]  = (const float*)d_in[base + 5 * l + 0];
    AS[l] = (const float*)d_in[base + 5 * l + 1];
    AT[l] = (const float*)d_in[base + 5 * l + 2];
    SK[l] = (const float*)d_in[base + 5 * l + 3];
    B[l]  = (const float*)d_in[base + 5 * l + 4];
  }
  const int* edges = (const int*)d_in[ei];
  const int* srcv = edges;
  const int* tgtv = edges + EDGES;
  float* out = (float*)d_out;

  char* ws = (char*)d_ws;
  u16* xbf = (u16*)(ws + OFF_XBF);
  u16* Cb  = (u16*)(ws + OFF_CB);
  u16* WT  = (u16*)(ws + OFF_WT);
  float* invd = (float*)(ws + OFF_WT);   // aliases WT: live only between attn_k and aggregate_k
  float* ss  = (float*)(ws + OFF_SS);
  float* stg = (float*)(ws + OFF_ST);
  float* alp = (float*)(ws + OFF_ALP);
  int* rp  = (int*)(ws + OFF_RP);
  int* cur = (int*)(ws + OFF_CUR);
  int* esr = (int*)(ws + OFF_ESR);

  // CSR build
  hipMemsetAsync(cur, 0, NODES * sizeof(int), stream);
  hist_k<<<(EDGES + 255) / 256, 256, 0, stream>>>(tgtv, cur);
  scan_k<<<1, 1024, 0, stream>>>(cur, rp);
  scatter_k<<<(EDGES + 255) / 256, 256, 0, stream>>>(srcv, tgtv, cur, esr);

  convert_x_k<<<45024, 256, 0, stream>>>(x, xbf);

  for (int l = 0; l < 3; ++l) {
    const int nbx = (l < 2) ? 12 : 7;
    const int ncat = nbx * 128;
    if (l < 2)
      prep_wcat_k<0><<<dim3(48, 24), 256, 0, stream>>>(W[l], SK[l], WT);
    else
      prep_wcat_k<1><<<dim3(28, 24), 256, 0, stream>>>(W[l], SK[l], WT);
    gemm_k<<<nbx * 469, 256, 0, stream>>>(xbf, WT, Cb, AS[l], AT[l], ss, stg, nbx, ncat);
    attn_k<<<(NODES + 255) / 256, 256, 0, stream>>>(rp, esr, ss, stg, alp, invd);
    if (l < 2)
      aggregate_k<0><<<15000, 256, 0, stream>>>(Cb, rp, esr, alp, invd, B[l], xbf, nullptr);
    else
      aggregate_k<1><<<15000, 256, 0, stream>>>(Cb, rp, esr, alp, invd, B[l], nullptr, out);
  }
}